// Round 6
// baseline (216.943 us; speedup 1.0000x reference)
//
#include <hip/hip_runtime.h>
#include <math.h>

#define EMA_A 0.99f
#define EMA_B 0.01f
#define THRESH 0.8f
#define EPS_F 1e-8f

#define NBLK2 512   // blocks in k_update (512 x 1024thr = 2 blocks/CU = 32 waves/CU)
#define RPB   16    // rows per block (M / NBLK2, M = 8192)

typedef float fx4 __attribute__((ext_vector_type(4)));

// ---------------------------------------------------------------------------
// ws layout (bytes):
//   [0]      int   hdr[0]=K, hdr[1]=filled_final
//   [1024]   int   slot_info[M]     (32 KB) -1=untouched else (src<<1)|exists
//   [33792]  float g_sumw           (4 B)   atomic sum of w
//   [35840]  float g1[C]            (8 KB)  atomic sum of w*x   per column
//   [44032]  float g2[C]            (8 KB)  atomic sum of w*x*x per column
// total ~52 KB
// ---------------------------------------------------------------------------

__global__ __launch_bounds__(1024)
void k_scan(const float* __restrict__ conf,
            const int* __restrict__ ptr0_p,
            const int* __restrict__ filled0_p,
            int* __restrict__ hdr,
            int* __restrict__ slot_info,
            float* __restrict__ g_sumw,
            float* __restrict__ g1,          // g1,g2 contiguous: zero 2C floats
            int B, int M, int C)
{
    const int tid  = threadIdx.x;        // 0..1023
    const int lane = tid & 63;

    // init slot_info + zero accumulators (ws is poisoned each launch)
    for (int m = tid; m < M; m += 1024) slot_info[m] = -1;
    for (int i = tid; i < 2 * C; i += 1024) g1[i] = 0.0f;
    if (tid == 0) *g_sumw = 0.0f;

    // load 8 confidences per thread, build high-mask
    const int base_i = tid * 8;
    int mask = 0;
    #pragma unroll
    for (int k = 0; k < 8; ++k) {
        int i = base_i + k;
        float c = (i < B) ? conf[i] : 0.0f;
        mask |= (c > THRESH) ? (1 << k) : 0;
    }
    int cnt = __popc(mask);

    __shared__ int s_cnt[1024];
    __shared__ int s_gbase[64];
    s_cnt[tid] = cnt;
    __syncthreads();

    // wave 0 scans 64 groups of 16 threads
    if (tid < 64) {
        int sum16 = 0;
        #pragma unroll
        for (int u = 0; u < 16; ++u) sum16 += s_cnt[tid * 16 + u];
        int v = sum16;
        #pragma unroll
        for (int d = 1; d < 64; d <<= 1) {
            int o = __shfl_up(v, d, 64);
            if (lane >= d) v += o;
        }
        s_gbase[tid] = v - sum16;           // exclusive group base
        if (tid == 63) hdr[0] = v;          // K
    }
    __syncthreads();
    const int K = hdr[0];

    // per-thread exclusive prefix of high-count
    int j = s_gbase[tid >> 4];
    for (int u = (tid & ~15); u < tid; ++u) j += s_cnt[u];

    // closed-form 'exists' as a function of write index j (data-independent):
    //   sweep 0: j in [0, L0)      -> p = P0+j, exists iff p < F0
    //   sweep 1: j in [L0, L0+M)   -> p = j-L0, exists iff p < F1
    //   sweep 2+:                  -> always exists
    int P0 = ((ptr0_p[0] % M) + M) % M;
    int F0 = filled0_p[0];
    if (F0 < 0) F0 = 0;
    if (F0 > M) F0 = M;
    const int L0 = M - P0;                         // writes in first sweep
    const int F1 = F0 + (M - (P0 > F0 ? P0 : F0)); // filled after first sweep

    #pragma unroll
    for (int k = 0; k < 8; ++k) {
        if (mask & (1 << k)) {
            int exist;
            if (j < L0)          exist = (P0 + j) < F0 ? 1 : 0;
            else if (j < L0 + M) exist = (j - L0) < F1 ? 1 : 0;
            else                 exist = 1;
            int p = (P0 + j) % M;
            slot_info[p] = ((base_i + k) << 1) | exist;
            ++j;
        }
    }

    if (tid == 0) {
        int n0 = K < L0 ? K : L0;
        int e0 = F0 - P0; if (e0 < 0) e0 = 0; if (e0 > n0) e0 = n0;
        int fresh0 = n0 - e0;
        int n1 = K - L0; if (n1 < 0) n1 = 0; if (n1 > M) n1 = M;
        int fresh1 = n1 - F1; if (fresh1 < 0) fresh1 = 0;
        int filled = F0 + fresh0 + fresh1;
        if (filled > M) filled = M;
        hdr[1] = filled;
    }
}

// ---------------------------------------------------------------------------

__global__ __launch_bounds__(1024)
void k_update(const float* __restrict__ mem_feat,
              const float* __restrict__ feat,
              const float* __restrict__ conf,
              const float* __restrict__ mem_conf,
              const int* __restrict__ slot_info,
              const int* __restrict__ hdr,
              float* __restrict__ out,
              float* __restrict__ g_sumw,
              float* __restrict__ g1,
              float* __restrict__ g2,
              int C)
{
    const int blk  = blockIdx.x, tid = threadIdx.x;
    const int half = tid >> 9;           // 0: even rows, 1: odd rows
    const int c4   = tid & 511;          // float4 slot within row (512 = C/4)
    const int c0   = c4 * 4;
    const int row0 = blk * RPB;

    __shared__ const float* s_src[RPB];  // primary source row
    __shared__ int   s_ema[RPB];         // 1 -> blend with mem row
    __shared__ float s_w[RPB];

    if (tid < RPB) {
        const int m = row0 + tid;
        const int info = slot_info[m];
        const int filled = hdr[1];
        const float mco = mem_conf[m];
        float mcu = mco;
        const float* src = mem_feat + (size_t)m * C;
        int ema = 0;
        if (info >= 0) {
            const float c = conf[info >> 1];
            src = feat + (size_t)(info >> 1) * C;
            if (info & 1) { mcu = EMA_A * mco + EMA_B * c; ema = 1; }
            else          { mcu = c; }                       // fresh: mem unused
        }
        s_src[tid] = src;
        s_ema[tid] = ema;
        s_w[tid]   = (m < filled) ? mcu : 0.0f;
    }
    __syncthreads();
    if (tid == 0) {
        float s = 0.0f;
        #pragma unroll
        for (int r = 0; r < RPB; ++r) s += s_w[r];
        atomicAdd(g_sumw, s);
    }

    fx4 s1 = {0.f, 0.f, 0.f, 0.f};
    fx4 s2 = {0.f, 0.f, 0.f, 0.f};

    #pragma unroll
    for (int rr = 0; rr < RPB / 2; ++rr) {
        const int r = rr * 2 + half;
        const int m = row0 + r;
        // branch-free primary load -> deep MLP across the unrolled loop
        fx4 x = *(const fx4*)(s_src[r] + c0);
        if (s_ema[r]) {                      // block-uniform, rare
            fx4 mv = *(const fx4*)(mem_feat + (size_t)m * C + c0);
            x = EMA_A * mv + EMA_B * x;
        }
        const float wv = s_w[r];
        s1 += wv * x;
        s2 += wv * x * x;
        __builtin_nontemporal_store(x, (fx4*)(out + (size_t)m * C + c0));
    }

    // combine the two halves in LDS, then one atomicAdd stream per column
    __shared__ fx4 st1[512], st2[512];       // 32 KB
    if (half == 1) { st1[c4] = s1; st2[c4] = s2; }
    __syncthreads();
    if (half == 0) {
        s1 += st1[c4];
        s2 += st2[c4];
        atomicAdd(&g1[c0 + 0], s1.x); atomicAdd(&g1[c0 + 1], s1.y);
        atomicAdd(&g1[c0 + 2], s1.z); atomicAdd(&g1[c0 + 3], s1.w);
        atomicAdd(&g2[c0 + 0], s2.x); atomicAdd(&g2[c0 + 1], s2.y);
        atomicAdd(&g2[c0 + 2], s2.z); atomicAdd(&g2[c0 + 3], s2.w);
    }
}

// ---------------------------------------------------------------------------

__global__ __launch_bounds__(256)
void k_fin(const float* __restrict__ g_sumw,
           const float* __restrict__ g1,
           const float* __restrict__ g2,
           float* __restrict__ out,
           int M, int C)
{
    const int c = blockIdx.x * 256 + threadIdx.x;
    if (c < C) {
        const double sumw  = (double)g_sumw[0];
        const double total = sumw + (double)EPS_F;
        const double s1 = (double)g1[c];
        const double s2 = (double)g2[c];
        const double mean = s1 / total;
        const double var  = (s2 - 2.0 * mean * s1 + mean * mean * sumw) / total;
        out[(size_t)M * C + c]       = (float)mean;
        out[(size_t)(M + 1) * C + c] = (float)sqrt(var + (double)EPS_F);
    }
}

// ---------------------------------------------------------------------------

extern "C" void kernel_launch(void* const* d_in, const int* in_sizes, int n_in,
                              void* d_out, int out_size, void* d_ws, size_t ws_size,
                              hipStream_t stream)
{
    const float* features     = (const float*)d_in[0];
    const float* confidence   = (const float*)d_in[1];
    const float* mem_features = (const float*)d_in[2];
    const float* mem_conf     = (const float*)d_in[3];
    const int*   ptr0         = (const int*)d_in[4];
    const int*   filled0      = (const int*)d_in[5];

    const int B = in_sizes[1];          // 8192
    const int M = in_sizes[3];          // 8192
    const int C = in_sizes[0] / B;      // 2048

    char* ws = (char*)d_ws;
    int*   hdr       = (int*)ws;
    int*   slot_info = (int*)(ws + 1024);
    float* g_sumw    = (float*)(ws + 33792);
    float* g1        = (float*)(ws + 35840);
    float* g2        = (float*)(ws + 44032);   // contiguous after g1

    float* out = (float*)d_out;

    k_scan<<<1, 1024, 0, stream>>>(confidence, ptr0, filled0, hdr, slot_info,
                                   g_sumw, g1, B, M, C);
    k_update<<<NBLK2, 1024, 0, stream>>>(mem_features, features, confidence, mem_conf,
                                         slot_info, hdr, out, g_sumw, g1, g2, C);
    k_fin<<<(C + 255) / 256, 256, 0, stream>>>(g_sumw, g1, g2, out, M, C);
}

// Round 9
// 180.458 us; speedup vs baseline: 1.2022x; 1.2022x over previous
//
#include <hip/hip_runtime.h>
#include <math.h>

#define EMA_A 0.99f
#define EMA_B 0.01f
#define THRESH 0.8f
#define EPS_F 1e-8f

#define NBLK2 1024  // blocks in k_update
#define RPB   8     // rows per block (M / NBLK2, M = 8192)

typedef float fx4 __attribute__((ext_vector_type(4)));

// ---------------------------------------------------------------------------
// ws layout (bytes):
//   [0]      int   hdr[0]=K, hdr[1]=filled_final
//   [1024]   int   slot_info[M]      (32 KB) -1=untouched else (src<<1)|exists
//   [33792]  float p0[NBLK2]         (4 KB)  per-block sum of w
//   [65536]  float p1[NBLK2*C]       (8 MB)  per-block per-col sum of w*x
//   [65536+8MB] float p2[NBLK2*C]    (8 MB)  per-block per-col sum of w*x*x
// total ~16.1 MB
// ---------------------------------------------------------------------------

__global__ __launch_bounds__(1024)
void k_scan(const float* __restrict__ conf,
            const int* __restrict__ ptr0_p,
            const int* __restrict__ filled0_p,
            int* __restrict__ hdr,
            int* __restrict__ slot_info,
            int B, int M)
{
    const int tid  = threadIdx.x;        // 0..1023
    const int lane = tid & 63;

    // init slot_info (ws is poisoned each launch)
    for (int m = tid; m < M; m += 1024) slot_info[m] = -1;

    // load 8 confidences per thread, build high-mask
    const int base_i = tid * 8;
    int mask = 0;
    #pragma unroll
    for (int k = 0; k < 8; ++k) {
        int i = base_i + k;
        float c = (i < B) ? conf[i] : 0.0f;
        mask |= (c > THRESH) ? (1 << k) : 0;
    }
    int cnt = __popc(mask);

    __shared__ int s_cnt[1024];
    __shared__ int s_gbase[64];
    s_cnt[tid] = cnt;
    __syncthreads();

    // wave 0 scans 64 groups of 16 threads
    if (tid < 64) {
        int sum16 = 0;
        #pragma unroll
        for (int u = 0; u < 16; ++u) sum16 += s_cnt[tid * 16 + u];
        int v = sum16;
        #pragma unroll
        for (int d = 1; d < 64; d <<= 1) {
            int o = __shfl_up(v, d, 64);
            if (lane >= d) v += o;
        }
        s_gbase[tid] = v - sum16;           // exclusive group base
        if (tid == 63) hdr[0] = v;          // K
    }
    __syncthreads();
    const int K = hdr[0];

    // per-thread exclusive prefix of high-count
    int j = s_gbase[tid >> 4];
    for (int u = (tid & ~15); u < tid; ++u) j += s_cnt[u];

    // closed-form 'exists' as a function of write index j (data-independent):
    //   sweep 0: j in [0, L0)      -> p = P0+j, exists iff p < F0
    //   sweep 1: j in [L0, L0+M)   -> p = j-L0, exists iff p < F1
    //   sweep 2+:                  -> always exists
    int P0 = ((ptr0_p[0] % M) + M) % M;
    int F0 = filled0_p[0];
    if (F0 < 0) F0 = 0;
    if (F0 > M) F0 = M;
    const int L0 = M - P0;                         // writes in first sweep
    const int F1 = F0 + (M - (P0 > F0 ? P0 : F0)); // filled after first sweep

    #pragma unroll
    for (int k = 0; k < 8; ++k) {
        if (mask & (1 << k)) {
            int exist;
            if (j < L0)          exist = (P0 + j) < F0 ? 1 : 0;
            else if (j < L0 + M) exist = (j - L0) < F1 ? 1 : 0;
            else                 exist = 1;
            int p = (P0 + j) % M;
            slot_info[p] = ((base_i + k) << 1) | exist;
            ++j;
        }
    }

    if (tid == 0) {
        int n0 = K < L0 ? K : L0;
        int e0 = F0 - P0; if (e0 < 0) e0 = 0; if (e0 > n0) e0 = n0;
        int fresh0 = n0 - e0;
        int n1 = K - L0; if (n1 < 0) n1 = 0; if (n1 > M) n1 = M;
        int fresh1 = n1 - F1; if (fresh1 < 0) fresh1 = 0;
        int filled = F0 + fresh0 + fresh1;
        if (filled > M) filled = M;
        hdr[1] = filled;
    }
}

// ---------------------------------------------------------------------------

__global__ __launch_bounds__(512)
void k_update(const float* __restrict__ mem_feat,
              const float* __restrict__ feat,
              const float* __restrict__ conf,
              const float* __restrict__ mem_conf,
              const int* __restrict__ slot_info,
              const int* __restrict__ hdr,
              float* __restrict__ out,
              float* __restrict__ p0,
              float* __restrict__ p1,
              float* __restrict__ p2,
              int C)
{
    const int blk  = blockIdx.x, tid = threadIdx.x;
    const int c0   = tid * 4;            // 512 threads x 4 = 2048 = C
    const int row0 = blk * RPB;

    __shared__ const float* s_src[RPB];  // primary source row
    __shared__ int   s_ema[RPB];         // 1 -> blend with mem row (rare)
    __shared__ float s_w[RPB];

    if (tid < RPB) {
        const int m = row0 + tid;
        const int info = slot_info[m];
        const int filled = hdr[1];
        const float mco = mem_conf[m];
        float mcu = mco;
        const float* src = mem_feat + (size_t)m * C;
        int ema = 0;
        if (info >= 0) {
            const float c = conf[info >> 1];
            src = feat + (size_t)(info >> 1) * C;
            if (info & 1) { mcu = EMA_A * mco + EMA_B * c; ema = 1; }
            else          { mcu = c; }                     // fresh: mem unused
        }
        s_src[tid] = src;
        s_ema[tid] = ema;
        s_w[tid]   = (m < filled) ? mcu : 0.0f;
    }
    __syncthreads();
    if (tid == 0) {
        float s = 0.0f;
        #pragma unroll
        for (int r = 0; r < RPB; ++r) s += s_w[r];
        p0[blk] = s;
    }

    // --- batch ALL 8 row-loads into registers: 8 loads in flight per thread ---
    fx4 x[RPB];
    #pragma unroll
    for (int r = 0; r < RPB; ++r)
        x[r] = *(const fx4*)(s_src[r] + c0);

    // rare block-uniform EMA fixup (second load L2/L3-resident)
    #pragma unroll
    for (int r = 0; r < RPB; ++r) {
        if (s_ema[r]) {
            fx4 mv = *(const fx4*)(mem_feat + (size_t)(row0 + r) * C + c0);
            x[r] = EMA_A * mv + EMA_B * x[r];
        }
    }

    fx4 s1 = {0.f, 0.f, 0.f, 0.f};
    fx4 s2 = {0.f, 0.f, 0.f, 0.f};
    #pragma unroll
    for (int r = 0; r < RPB; ++r) {
        const float wv = s_w[r];
        s1 += wv * x[r];
        s2 += wv * x[r] * x[r];
        __builtin_nontemporal_store(x[r], (fx4*)(out + (size_t)(row0 + r) * C + c0));
    }

    const size_t pb = (size_t)blk * C;
    *(fx4*)(p1 + pb + c0) = s1;
    *(fx4*)(p2 + pb + c0) = s2;
}

// ---------------------------------------------------------------------------
// 32 blocks x 1024 thr; block owns 64 consecutive columns, 16 row-chunks.
// Coalesced: threads 0..63 read 64 consecutive floats (256 B).

__global__ __launch_bounds__(1024)
void k_stats(const float* __restrict__ p0,
             const float* __restrict__ p1,
             const float* __restrict__ p2,
             float* __restrict__ out,
             int M, int C)
{
    const int tid   = threadIdx.x;
    const int col   = blockIdx.x * 64 + (tid & 63);  // 0..C-1
    const int chunk = tid >> 6;                      // 0..15

    // deterministic sumw reduce over NBLK2 per-block partials (redundant/block)
    __shared__ float s_swp[16];
    float sw = (tid < NBLK2) ? p0[tid] : 0.0f;
    #pragma unroll
    for (int d = 32; d >= 1; d >>= 1) sw += __shfl_down(sw, d, 64);
    if ((tid & 63) == 0) s_swp[tid >> 6] = sw;

    double s1 = 0.0, s2 = 0.0;
    for (int i = 0; i < NBLK2 / 16; ++i) {
        const int b = chunk * (NBLK2 / 16) + i;
        s1 += (double)p1[(size_t)b * C + col];
        s2 += (double)p2[(size_t)b * C + col];
    }
    __shared__ double l1[1024], l2[1024];
    l1[tid] = s1;
    l2[tid] = s2;
    __syncthreads();
    if (chunk == 0) {
        #pragma unroll
        for (int q = 1; q < 16; ++q) {
            s1 += l1[tid + 64 * q];
            s2 += l2[tid + 64 * q];
        }
        float swt = 0.0f;
        #pragma unroll
        for (int u = 0; u < 16; ++u) swt += s_swp[u];
        const double sumw  = (double)swt;
        const double total = sumw + (double)EPS_F;
        const double mean  = s1 / total;
        const double var   = (s2 - 2.0 * mean * s1 + mean * mean * sumw) / total;
        out[(size_t)M * C + col]       = (float)mean;
        out[(size_t)(M + 1) * C + col] = (float)sqrt(var + (double)EPS_F);
    }
}

// ---------------------------------------------------------------------------

extern "C" void kernel_launch(void* const* d_in, const int* in_sizes, int n_in,
                              void* d_out, int out_size, void* d_ws, size_t ws_size,
                              hipStream_t stream)
{
    const float* features     = (const float*)d_in[0];
    const float* confidence   = (const float*)d_in[1];
    const float* mem_features = (const float*)d_in[2];
    const float* mem_conf     = (const float*)d_in[3];
    const int*   ptr0         = (const int*)d_in[4];
    const int*   filled0      = (const int*)d_in[5];

    const int B = in_sizes[1];          // 8192
    const int M = in_sizes[3];          // 8192
    const int C = in_sizes[0] / B;      // 2048

    char* ws = (char*)d_ws;
    int*   hdr       = (int*)ws;
    int*   slot_info = (int*)(ws + 1024);
    float* p0        = (float*)(ws + 33792);
    float* p1        = (float*)(ws + 65536);
    float* p2        = (float*)(ws + 65536 + 4 * (size_t)NBLK2 * C);

    float* out = (float*)d_out;

    k_scan<<<1, 1024, 0, stream>>>(confidence, ptr0, filled0, hdr, slot_info, B, M);
    k_update<<<NBLK2, 512, 0, stream>>>(mem_features, features, confidence, mem_conf,
                                        slot_info, hdr, out, p0, p1, p2, C);
    k_stats<<<C / 64, 1024, 0, stream>>>(p0, p1, p2, out, M, C);
}